// Round 10
// baseline (1313.710 us; speedup 1.0000x reference)
//
#include <hip/hip_runtime.h>

#define T_STEPS 100
#define B_SIZE  512
#define I_SIZE  700
#define H_SIZE  512
#define O_SIZE  20
#define NT      256    // threads/block; each owns neurons tid and tid+256

#define ALPHA 0.8187307530779818f   // exp(-0.001/0.005) rounded to f32
#define BETA  0.9048374180359595f   // exp(-0.001/0.010) rounded to f32
#define REG   1e-7

__device__ __forceinline__ int rfl(int x) { return __builtin_amdgcn_readfirstlane(x); }

// residue-routed add for one (lo,hi) neuron pair; chains e{r}{l,h}
#define RES2(ii, wl, wh)                                                    \
    switch ((ii) & 3) {                                                     \
        case 0:  e0l=__fadd_rn(e0l,(wl)); e0h=__fadd_rn(e0h,(wh)); break;   \
        case 1:  e1l=__fadd_rn(e1l,(wl)); e1h=__fadd_rn(e1h,(wh)); break;   \
        case 2:  e2l=__fadd_rn(e2l,(wl)); e2h=__fadd_rn(e2h,(wh)); break;   \
        default: e3l=__fadd_rn(e3l,(wl)); e3h=__fadd_rn(e3h,(wh)); break;   \
    }

#define RES_ADD(ii, ww)                                              \
    switch ((ii) & 3) {                                              \
        case 0:  e0 = __fadd_rn(e0, (ww)); break;                    \
        case 1:  e1 = __fadd_rn(e1, (ww)); break;                    \
        case 2:  e2 = __fadd_rn(e2, (ww)); break;                    \
        default: e3 = __fadd_rn(e3, (ww)); break;                    \
    }

// ---- BLAS-semantics sequential chains for a neuron pair, int4-batched ----
__device__ __forceinline__ void seq2(const int* __restrict__ idxs, int n,
                                     const float* __restrict__ W, int tid,
                                     float& A, float& B) {
    float al = 0.f, ah = 0.f;
    int k = 0;
    for (; k + 4 <= n; k += 4) {
        int4 q = *(const int4*)&idxs[k];
        int i0 = rfl(q.x), i1 = rfl(q.y), i2 = rfl(q.z), i3 = rfl(q.w);
        const float* p0 = W + (size_t)i0 * H_SIZE + tid;
        const float* p1 = W + (size_t)i1 * H_SIZE + tid;
        const float* p2 = W + (size_t)i2 * H_SIZE + tid;
        const float* p3 = W + (size_t)i3 * H_SIZE + tid;
        float w0l = p0[0], w0h = p0[256];
        float w1l = p1[0], w1h = p1[256];
        float w2l = p2[0], w2h = p2[256];
        float w3l = p3[0], w3h = p3[256];
        al = __fadd_rn(al, w0l); ah = __fadd_rn(ah, w0h);
        al = __fadd_rn(al, w1l); ah = __fadd_rn(ah, w1h);
        al = __fadd_rn(al, w2l); ah = __fadd_rn(ah, w2h);
        al = __fadd_rn(al, w3l); ah = __fadd_rn(ah, w3h);
    }
    for (; k < n; ++k) {
        int i = rfl(idxs[k]);
        const float* p = W + (size_t)i * H_SIZE + tid;
        al = __fadd_rn(al, p[0]); ah = __fadd_rn(ah, p[256]);
    }
    A = al; B = ah;
}

// ---------------- transpose: out[c*R + r] = in[r*C + c] ----------------
__global__ void transpose_kernel(const float* __restrict__ in,
                                 float* __restrict__ out, int R, int C) {
    int idx = blockIdx.x * blockDim.x + threadIdx.x;
    if (idx < R * C) {
        int r = idx / C, c = idx % C;
        out[c * R + r] = in[r * C + c];
    }
}

__global__ void init_counts_kernel(int* __restrict__ g) {
    int tid = threadIdx.x;
    if (tid < 2 * H_SIZE) g[tid] = 0;
}

// ---------------- main SNN kernel: one block per batch element ----------------
// Bitwise-identical arithmetic to the verified R7-R9 engine model:
//   einsum dots: mod-4 residue chains ascending, (L0+L1)+(L2+L3);
//   BLAS dots: ascending sequential chains, two results added f32;
//   states/filter: rn mul-then-add in reference order.
// Perf: 2 neurons/thread (amortized idx/addr/switch, 2x ILP), int4 idx
// batching, 2 barriers/step, deferred parallel readout.
__global__ __launch_bounds__(NT, 1)
void snn_pair_kernel(const float* __restrict__ spikes,   // (B,T,I)
                     const float* __restrict__ W0T,      // (I,H)
                     const float* __restrict__ W1T,      // (H,H)
                     const float* __restrict__ WrecT,    // (H,H)
                     const float* __restrict__ WoutT,    // (H,O)
                     const float* __restrict__ bout,     // (O)
                     float* __restrict__ out,            // (B,T+1,O)
                     int* __restrict__ gcnt0,            // (H)
                     int* __restrict__ gcnt1)            // (H)
{
    const int tid  = threadIdx.x;          // 0..255
    const int b    = blockIdx.x;
    const int lane = tid & 63;
    const int wave = tid >> 6;             // 0..3
    const unsigned long long lt = (1ULL << lane) - 1ULL;

    __shared__ __align__(16) int inIdx[I_SIZE];
    __shared__ __align__(16) int l0Idx[H_SIZE];
    __shared__ __align__(16) int l1A[H_SIZE];
    __shared__ __align__(16) int l1B[H_SIZE];
    __shared__ int waveCnt[4][8];          // [wave][group]
    __shared__ unsigned long long maskT[T_STEPS][8];  // layer-1 ballots (h-order)
    __shared__ float h2buf[T_STEPS][O_SIZE];

    float m0l=0.f,s0l=0.f,m1l=0.f,s1l=0.f;    // neuron h = tid
    float m0h=0.f,s0h=0.f,m1h=0.f,s1h=0.f;    // neuron h = tid+256
    int   c0l=0,c0h=0,c1l=0,c1h=0;

    int* l1Prev = l1A;
    int* l1Cur  = l1B;
    int  n1Prev = 0;

    const float* srow = spikes + (size_t)b * T_STEPS * I_SIZE;

    float spA = srow[tid];
    float spB = srow[256 + tid];
    float spC = (tid < I_SIZE - 512) ? srow[512 + tid] : 0.f;

    for (int t = 0; t < T_STEPS; ++t) {
        int fA  = (spA != 0.f);
        int fB  = (spB != 0.f);
        int fC  = (spC != 0.f);
        int f0l = ((m0l - 1.0f) > 0.0f), f0h = ((m0h - 1.0f) > 0.0f);
        int f1l = ((m1l - 1.0f) > 0.0f), f1h = ((m1h - 1.0f) > 0.0f);

        unsigned long long bA  = __ballot(fA),  bB  = __ballot(fB), bC = __ballot(fC);
        unsigned long long b0l = __ballot(f0l), b0h = __ballot(f0h);
        unsigned long long b1l = __ballot(f1l), b1h = __ballot(f1h);
        if (lane == 0) {
            int* wc = waveCnt[wave];
            wc[0] = __popcll(bA);  wc[1] = __popcll(bB);  wc[2] = __popcll(bC);
            wc[3] = __popcll(b0l); wc[4] = __popcll(b0h);
            wc[5] = __popcll(b1l); wc[6] = __popcll(b1h);
            maskT[t][wave]     = b1l;
            maskT[t][4 + wave] = b1h;
        }
        __syncthreads();                                   // sync 1

        // redundant per-thread prefix over 4 waves x 7 groups
        int nA=0,nB=0,nC=0,n0lo=0,n0hi=0,n1lo=0,n1hi=0;
        int oA=0,oB=0,oC=0,o0l=0,o0h=0,o1l=0,o1h=0;
        #pragma unroll
        for (int w = 0; w < 4; ++w) {
            const int* wc = waveCnt[w];
            if (w == wave) { oA=nA; oB=nB; oC=nC; o0l=n0lo; o0h=n0hi; o1l=n1lo; o1h=n1hi; }
            nA+=wc[0]; nB+=wc[1]; nC+=wc[2];
            n0lo+=wc[3]; n0hi+=wc[4]; n1lo+=wc[5]; n1hi+=wc[6];
        }
        const int nIn   = nA + nB + nC;
        const int n0    = n0lo + n0hi;
        const int n1Cur = n1lo + n1hi;

        // order-preserving scatter: A(0..255), B(256..511), C(512..699) ascending
        if (fA)  inIdx[oA + __popcll(bA & lt)]            = tid;
        if (fB)  inIdx[nA + oB + __popcll(bB & lt)]       = 256 + tid;
        if (fC)  inIdx[nA + nB + oC + __popcll(bC & lt)]  = 512 + tid;
        if (f0l) l0Idx[o0l + __popcll(b0l & lt)]          = tid;
        if (f0h) l0Idx[n0lo + o0h + __popcll(b0h & lt)]   = 256 + tid;
        if (f1l) l1Cur[o1l + __popcll(b1l & lt)]          = tid;
        if (f1h) l1Cur[n1lo + o1h + __popcll(b1h & lt)]   = 256 + tid;
        __syncthreads();                                   // sync 2

        // prefetch next step's spikes
        if (t + 1 < T_STEPS) {
            spA = srow[(t+1)*I_SIZE + tid];
            spB = srow[(t+1)*I_SIZE + 256 + tid];
            spC = (tid < I_SIZE - 512) ? srow[(t+1)*I_SIZE + 512 + tid] : 0.f;
        }

        // ---- cur0 (einsum semantics) for both neurons ----
        float e0l=0.f,e1l=0.f,e2l=0.f,e3l=0.f;
        float e0h=0.f,e1h=0.f,e2h=0.f,e3h=0.f;
        {
            int k = 0;
            for (; k + 4 <= nIn; k += 4) {
                int4 q = *(const int4*)&inIdx[k];
                int i0 = rfl(q.x), i1 = rfl(q.y), i2 = rfl(q.z), i3 = rfl(q.w);
                const float* p0 = W0T + (size_t)i0 * H_SIZE + tid;
                const float* p1 = W0T + (size_t)i1 * H_SIZE + tid;
                const float* p2 = W0T + (size_t)i2 * H_SIZE + tid;
                const float* p3 = W0T + (size_t)i3 * H_SIZE + tid;
                float w0l = p0[0], w0h = p0[256];
                float w1l = p1[0], w1h = p1[256];
                float w2l = p2[0], w2h = p2[256];
                float w3l = p3[0], w3h = p3[256];
                RES2(i0, w0l, w0h); RES2(i1, w1l, w1h);
                RES2(i2, w2l, w2h); RES2(i3, w3l, w3h);
            }
            for (; k < nIn; ++k) {
                int i = rfl(inIdx[k]);
                const float* p = W0T + (size_t)i * H_SIZE + tid;
                float wl = p[0], wh = p[256];
                RES2(i, wl, wh);
            }
        }
        float cur0l = __fadd_rn(__fadd_rn(e0l, e1l), __fadd_rn(e2l, e3l));
        float cur0h = __fadd_rn(__fadd_rn(e0h, e1h), __fadd_rn(e2h, e3h));

        // ---- cur1 (BLAS semantics) ----
        float a1l, a1h, arl, arh;
        seq2(l0Idx, n0, W1T, tid, a1l, a1h);
        seq2(l1Prev, n1Prev, WrecT, tid, arl, arh);
        float cur1l = __fadd_rn(a1l, arl);
        float cur1h = __fadd_rn(a1h, arh);

        // ---- LIF updates: rn mul-then-add, reference order ----
        float ns0l = __fadd_rn(__fmul_rn(ALPHA, s0l), cur0l);
        float nm0l = __fmul_rn(__fadd_rn(__fmul_rn(BETA, m0l), s0l), 1.0f - (float)f0l);
        float ns1l = __fadd_rn(__fmul_rn(ALPHA, s1l), cur1l);
        float nm1l = __fmul_rn(__fadd_rn(__fmul_rn(BETA, m1l), s1l), 1.0f - (float)f1l);
        s0l=ns0l; m0l=nm0l; s1l=ns1l; m1l=nm1l;

        float ns0h = __fadd_rn(__fmul_rn(ALPHA, s0h), cur0h);
        float nm0h = __fmul_rn(__fadd_rn(__fmul_rn(BETA, m0h), s0h), 1.0f - (float)f0h);
        float ns1h = __fadd_rn(__fmul_rn(ALPHA, s1h), cur1h);
        float nm1h = __fmul_rn(__fadd_rn(__fmul_rn(BETA, m1h), s1h), 1.0f - (float)f1h);
        s0h=ns0h; m0h=nm0h; s1h=ns1h; m1h=nm1h;

        c0l+=f0l; c0h+=f0h; c1l+=f1l; c1h+=f1h;

        int* tmp = l1Prev; l1Prev = l1Cur; l1Cur = tmp;
        n1Prev = n1Cur;
    }

    atomicAdd(&gcnt0[tid], c0l);       atomicAdd(&gcnt0[tid + 256], c0h);
    atomicAdd(&gcnt1[tid], c1l);       atomicAdd(&gcnt1[tid + 256], c1h);
    __syncthreads();   // all maskT writes complete

    // ---- phase 2: h2[t][o] in parallel, einsum semantics (ascending bits) ----
    {
        int grp = tid / O_SIZE;        // 0..12 (tid 240..255 idle)
        int o   = tid % O_SIZE;
        if (grp < 12) {
            for (int tt = grp; tt < T_STEPS; tt += 12) {
                float e0=0.f, e1=0.f, e2=0.f, e3=0.f;
                #pragma unroll
                for (int j = 0; j < 8; ++j) {
                    unsigned long long m = maskT[tt][j];
                    int base = j * 64;               // j<4: h 0..255; j>=4: 256..511
                    while (m) {
                        int idx = base + (int)__builtin_ctzll(m);
                        m &= m - 1;
                        float wv = WoutT[(size_t)idx * O_SIZE + o];
                        RES_ADD(idx, wv);
                    }
                }
                h2buf[tt][o] = __fadd_rn(__fadd_rn(e0, e1), __fadd_rn(e2, e3));
            }
        }
    }
    __syncthreads();

    // ---- phase 3: double-exp filter recurrence (20 threads) ----
    if (tid < O_SIZE) {
        float bo  = bout[tid];
        float flt = 0.f, outv = 0.f;
        out[((size_t)b * (T_STEPS + 1)) * O_SIZE + tid] = bo;   // t = 0 row
        for (int tt = 0; tt < T_STEPS; ++tt) {
            float h2   = h2buf[tt][tid];
            float nflt = __fadd_rn(__fmul_rn(ALPHA, flt), h2);
            float nout = __fadd_rn(__fmul_rn(BETA, outv), flt);  // OLD flt
            flt = nflt; outv = nout;
            out[((size_t)b * (T_STEPS + 1) + (tt + 1)) * O_SIZE + tid] = __fadd_rn(nout, bo);
        }
    }
}

// ---------------- reg loss ----------------
__global__ void reg_kernel(const int* __restrict__ g0,
                           const int* __restrict__ g1,
                           float* __restrict__ out_reg) {
    int tid = threadIdx.x;     // 512 threads
    double v0 = (double)g0[tid], v1 = (double)g1[tid];
    double tot = v0 + v1;
    double sq  = v0 * v0 + v1 * v1;
    for (int off = 32; off; off >>= 1) {
        tot += __shfl_down(tot, off, 64);
        sq  += __shfl_down(sq,  off, 64);
    }
    __shared__ double stot[8], ssq[8];
    if ((tid & 63) == 0) { stot[tid >> 6] = tot; ssq[tid >> 6] = sq; }
    __syncthreads();
    if (tid == 0) {
        double Tt = 0.0, Sq = 0.0;
        for (int w = 0; w < 8; ++w) { Tt += stot[w]; Sq += ssq[w]; }
        double reg = REG * (Tt / 26214400.0 + Sq / 512.0);
        *out_reg = (float)reg;
    }
}

extern "C" void kernel_launch(void* const* d_in, const int* in_sizes, int n_in,
                              void* d_out, int out_size, void* d_ws, size_t ws_size,
                              hipStream_t stream) {
    const float* spikes = (const float*)d_in[0];   // (512,100,700)
    const float* W0     = (const float*)d_in[1];   // (512,700)
    const float* W1     = (const float*)d_in[2];   // (512,512)
    const float* Wrec   = (const float*)d_in[3];   // (512,512)
    const float* Wout   = (const float*)d_in[4];   // (20,512)
    const float* bout   = (const float*)d_in[5];   // (20,)
    float* out = (float*)d_out;

    float* W0T   = (float*)d_ws;                       // 700*512 f32
    float* W1T   = W0T   + (size_t)I_SIZE * H_SIZE;    // 512*512
    float* WrecT = W1T   + (size_t)H_SIZE * H_SIZE;    // 512*512
    float* WoutT = WrecT + (size_t)H_SIZE * H_SIZE;    // 512*20
    int*   gcnt0 = (int*)(WoutT + (size_t)H_SIZE * O_SIZE);
    int*   gcnt1 = gcnt0 + H_SIZE;

    int n;
    n = H_SIZE * I_SIZE;
    transpose_kernel<<<(n + 255) / 256, 256, 0, stream>>>(W0, W0T, H_SIZE, I_SIZE);
    n = H_SIZE * H_SIZE;
    transpose_kernel<<<(n + 255) / 256, 256, 0, stream>>>(W1, W1T, H_SIZE, H_SIZE);
    transpose_kernel<<<(n + 255) / 256, 256, 0, stream>>>(Wrec, WrecT, H_SIZE, H_SIZE);
    n = O_SIZE * H_SIZE;
    transpose_kernel<<<(n + 255) / 256, 256, 0, stream>>>(Wout, WoutT, O_SIZE, H_SIZE);

    init_counts_kernel<<<1, 1024, 0, stream>>>(gcnt0);

    snn_pair_kernel<<<B_SIZE, NT, 0, stream>>>(spikes, W0T, W1T, WrecT, WoutT,
                                               bout, out, gcnt0, gcnt1);

    reg_kernel<<<1, H_SIZE, 0, stream>>>(gcnt0, gcnt1,
                                         out + (size_t)B_SIZE * (T_STEPS + 1) * O_SIZE);
}

// Round 11
// 882.227 us; speedup vs baseline: 1.4891x; 1.4891x over previous
//
#include <hip/hip_runtime.h>

#define T_STEPS 100
#define B_SIZE  512
#define I_SIZE  700
#define H_SIZE  512
#define O_SIZE  20

#define ALPHA 0.8187307530779818f   // exp(-0.001/0.005) rounded to f32
#define BETA  0.9048374180359595f   // exp(-0.001/0.010) rounded to f32
#define REG   1e-7

#define RES_ADD(ii, ww)                                              \
    switch ((ii) & 3) {                                              \
        case 0:  e0 = __fadd_rn(e0, (ww)); break;                    \
        case 1:  e1 = __fadd_rn(e1, (ww)); break;                    \
        case 2:  e2 = __fadd_rn(e2, (ww)); break;                    \
        default: e3 = __fadd_rn(e3, (ww)); break;                    \
    }

// ---- BLAS-semantics ascending sequential chain over byte-offset list ----
// Per element: v_add (off+tid4) + global_load(saddr) + fadd. No rfl, no SALU.
__device__ __forceinline__ float seq_off(const int* __restrict__ lst, int n,
                                         const char* __restrict__ Wb, int tid4) {
    float a = 0.f;
    int k = 0;
    for (; k + 8 <= n; k += 8) {
        int4 q0 = *(const int4*)&lst[k];
        int4 q1 = *(const int4*)&lst[k + 4];
        float w0 = *(const float*)(Wb + (unsigned)(q0.x + tid4));
        float w1 = *(const float*)(Wb + (unsigned)(q0.y + tid4));
        float w2 = *(const float*)(Wb + (unsigned)(q0.z + tid4));
        float w3 = *(const float*)(Wb + (unsigned)(q0.w + tid4));
        float w4 = *(const float*)(Wb + (unsigned)(q1.x + tid4));
        float w5 = *(const float*)(Wb + (unsigned)(q1.y + tid4));
        float w6 = *(const float*)(Wb + (unsigned)(q1.z + tid4));
        float w7 = *(const float*)(Wb + (unsigned)(q1.w + tid4));
        a = __fadd_rn(a, w0); a = __fadd_rn(a, w1);
        a = __fadd_rn(a, w2); a = __fadd_rn(a, w3);
        a = __fadd_rn(a, w4); a = __fadd_rn(a, w5);
        a = __fadd_rn(a, w6); a = __fadd_rn(a, w7);
    }
    for (; k < n; ++k) {
        float w = *(const float*)(Wb + (unsigned)(lst[k] + tid4));
        a = __fadd_rn(a, w);
    }
    return a;
}

// ---- one einsum residue chain: ascending within the residue class ----
__device__ __forceinline__ float res_chain(const int* __restrict__ lst, int n,
                                           const char* __restrict__ Wb, int tid4) {
    float e = 0.f;
    int k = 0;
    for (; k + 4 <= n; k += 4) {
        int4 q = *(const int4*)&lst[k];
        float w0 = *(const float*)(Wb + (unsigned)(q.x + tid4));
        float w1 = *(const float*)(Wb + (unsigned)(q.y + tid4));
        float w2 = *(const float*)(Wb + (unsigned)(q.z + tid4));
        float w3 = *(const float*)(Wb + (unsigned)(q.w + tid4));
        e = __fadd_rn(e, w0); e = __fadd_rn(e, w1);
        e = __fadd_rn(e, w2); e = __fadd_rn(e, w3);
    }
    for (; k < n; ++k) {
        float w = *(const float*)(Wb + (unsigned)(lst[k] + tid4));
        e = __fadd_rn(e, w);
    }
    return e;
}

// ---------------- transpose: out[c*R + r] = in[r*C + c] ----------------
__global__ void transpose_kernel(const float* __restrict__ in,
                                 float* __restrict__ out, int R, int C) {
    int idx = blockIdx.x * blockDim.x + threadIdx.x;
    if (idx < R * C) {
        int r = idx / C, c = idx % C;
        out[c * R + r] = in[r * C + c];
    }
}

__global__ void init_counts_kernel(int* __restrict__ g) {
    int tid = threadIdx.x;
    if (tid < 2 * H_SIZE) g[tid] = 0;
}

// ---------------- main SNN kernel: one block per batch element ----------------
// Bitwise-identical arithmetic to the verified R7-R9 engine model:
//   einsum dots (cur0, h2): mod-4 residue chains ascending, (L0+L1)+(L2+L3);
//   BLAS dots (cur1): ascending sequential chains, two results added f32;
//   states/filter: rn mul-then-add in reference order.
// Perf: byte-offset lists + VGPR voffset addressing (no rfl/SALU per term),
// residue-partitioned input lists (no per-element switch), int4 batching,
// 512 threads (16 waves/CU), deferred parallel readout.
__global__ __launch_bounds__(512, 1)
void snn_sparse3_kernel(const float* __restrict__ spikes,   // (B,T,I)
                        const float* __restrict__ W0T,      // (I,H)
                        const float* __restrict__ W1T,      // (H,H)
                        const float* __restrict__ WrecT,    // (H,H)
                        const float* __restrict__ WoutT,    // (H,O)
                        const float* __restrict__ bout,     // (O)
                        float* __restrict__ out,            // (B,T+1,O)
                        int* __restrict__ gcnt0,            // (H)
                        int* __restrict__ gcnt1)            // (H)
{
    const int tid  = threadIdx.x;          // h index, 0..511
    const int b    = blockIdx.x;
    const int lane = tid & 63;
    const int wave = tid >> 6;             // 0..7
    const int res  = tid & 3;              // == lane & 3
    const int tid4 = tid << 2;
    const unsigned long long lt = (1ULL << lane) - 1ULL;
    const unsigned long long RM = 0x1111111111111111ULL << res;  // own-residue lanes

    __shared__ __align__(16) int listIn[4][176];   // einsum inputs by residue
    __shared__ __align__(16) int l0Idx[H_SIZE];
    __shared__ __align__(16) int l1A[H_SIZE];
    __shared__ __align__(16) int l1B[H_SIZE];
    __shared__ __align__(16) int cntA[8][4];       // [wave][res]
    __shared__ __align__(16) int cntB[4][4];       // waves 0..2 only (3 unused)
    __shared__ int cnt0[8], cnt1[8];
    __shared__ unsigned long long maskT[T_STEPS][8];
    __shared__ float h2buf[T_STEPS][O_SIZE];

    float m0 = 0.f, s0 = 0.f, m1 = 0.f, s1 = 0.f;
    int   c0 = 0, c1 = 0;

    int* l1Prev = l1A;
    int* l1Cur  = l1B;
    int  n1Prev = 0;

    const char* W0b = (const char*)W0T;
    const char* W1b = (const char*)W1T;
    const char* Wrb = (const char*)WrecT;

    const float* srow = spikes + (size_t)b * T_STEPS * I_SIZE;

    float spA = srow[tid];
    float spB = (tid < I_SIZE - H_SIZE) ? srow[H_SIZE + tid] : 0.f;

    for (int t = 0; t < T_STEPS; ++t) {
        int fA = (spA != 0.f);
        int fB = (spB != 0.f);
        int f0 = ((m0 - 1.0f) > 0.0f);
        int f1 = ((m1 - 1.0f) > 0.0f);

        unsigned long long bA = __ballot(fA);
        unsigned long long bB = __ballot(fB);
        unsigned long long b0 = __ballot(f0);
        unsigned long long b1 = __ballot(f1);
        if (lane == 0) {
            const unsigned long long R0 = 0x1111111111111111ULL;
            cntA[wave][0] = __popcll(bA & R0);
            cntA[wave][1] = __popcll(bA & (R0 << 1));
            cntA[wave][2] = __popcll(bA & (R0 << 2));
            cntA[wave][3] = __popcll(bA & (R0 << 3));
            if (wave < 3) {
                cntB[wave][0] = __popcll(bB & R0);
                cntB[wave][1] = __popcll(bB & (R0 << 1));
                cntB[wave][2] = __popcll(bB & (R0 << 2));
                cntB[wave][3] = __popcll(bB & (R0 << 3));
            }
            cnt0[wave] = __popcll(b0);
            cnt1[wave] = __popcll(b1);
            maskT[t][wave] = b1;
        }
        __syncthreads();                                   // sync 1

        // ---- per-thread prefix: totals for all residues, offsets for own ----
        int nA0=0,nA1=0,nA2=0,nA3=0, oA_mine=0;
        #pragma unroll
        for (int w = 0; w < 8; ++w) {
            int4 c = *(const int4*)cntA[w];
            if (w == wave)
                oA_mine = (res == 0) ? nA0 : (res == 1) ? nA1 : (res == 2) ? nA2 : nA3;
            nA0 += c.x; nA1 += c.y; nA2 += c.z; nA3 += c.w;
        }
        int nB0=0,nB1=0,nB2=0,nB3=0, oB_mine=0;
        #pragma unroll
        for (int w = 0; w < 3; ++w) {
            int4 c = *(const int4*)cntB[w];
            if (w == wave)
                oB_mine = (res == 0) ? nB0 : (res == 1) ? nB1 : (res == 2) ? nB2 : nB3;
            nB0 += c.x; nB1 += c.y; nB2 += c.z; nB3 += c.w;
        }
        int n0 = 0, o0 = 0, n1Cur = 0, o1 = 0;
        #pragma unroll
        for (int w = 0; w < 8; ++w) {
            if (w == wave) { o0 = n0; o1 = n1Cur; }
            n0 += cnt0[w]; n1Cur += cnt1[w];
        }
        const int nR0 = nA0 + nB0, nR1 = nA1 + nB1, nR2 = nA2 + nB2, nR3 = nA3 + nB3;
        const int nA_mine = (res == 0) ? nA0 : (res == 1) ? nA1 : (res == 2) ? nA2 : nA3;

        // ---- order-preserving scatter of byte offsets (ascending per list) ----
        if (fA) listIn[res][oA_mine + __popcll(bA & RM & lt)] = tid << 11;
        if (fB) listIn[res][nA_mine + oB_mine + __popcll(bB & RM & lt)] = (H_SIZE + tid) << 11;
        if (f0) l0Idx[o0 + __popcll(b0 & lt)] = tid << 11;
        if (f1) l1Cur[o1 + __popcll(b1 & lt)] = tid << 11;
        __syncthreads();                                   // sync 2

        // prefetch next step's spikes
        if (t + 1 < T_STEPS) {
            spA = srow[(t + 1) * I_SIZE + tid];
            spB = (tid < I_SIZE - H_SIZE) ? srow[(t + 1) * I_SIZE + H_SIZE + tid] : 0.f;
        }

        // ---- cur0 (einsum semantics): 4 residue chains, combine ----
        float e0 = res_chain(listIn[0], nR0, W0b, tid4);
        float e1 = res_chain(listIn[1], nR1, W0b, tid4);
        float e2 = res_chain(listIn[2], nR2, W0b, tid4);
        float e3 = res_chain(listIn[3], nR3, W0b, tid4);
        float cur0 = __fadd_rn(__fadd_rn(e0, e1), __fadd_rn(e2, e3));

        // ---- cur1 (BLAS semantics): two ascending chains, results added ----
        float a1 = seq_off(l0Idx, n0, W1b, tid4);
        float ar = seq_off(l1Prev, n1Prev, Wrb, tid4);
        float cur1 = __fadd_rn(a1, ar);

        // ---- LIF updates: rn mul-then-add, reference order ----
        float ns0 = __fadd_rn(__fmul_rn(ALPHA, s0), cur0);
        float nm0 = __fmul_rn(__fadd_rn(__fmul_rn(BETA, m0), s0), 1.0f - (float)f0);
        float ns1 = __fadd_rn(__fmul_rn(ALPHA, s1), cur1);
        float nm1 = __fmul_rn(__fadd_rn(__fmul_rn(BETA, m1), s1), 1.0f - (float)f1);
        s0 = ns0; m0 = nm0; s1 = ns1; m1 = nm1;
        c0 += f0; c1 += f1;

        int* tmp = l1Prev; l1Prev = l1Cur; l1Cur = tmp;
        n1Prev = n1Cur;
    }

    atomicAdd(&gcnt0[tid], c0);
    atomicAdd(&gcnt1[tid], c1);
    __syncthreads();   // all maskT writes complete

    // ---- phase 2: h2[t][o] in parallel (einsum semantics, ascending bits) ----
    {
        int grp = tid / O_SIZE;        // 0..25 (threads 500..511 idle)
        int o   = tid % O_SIZE;
        if (grp < 25) {
            for (int tt = grp; tt < T_STEPS; tt += 25) {
                float e0 = 0.f, e1 = 0.f, e2 = 0.f, e3 = 0.f;
                #pragma unroll
                for (int j = 0; j < 8; ++j) {
                    unsigned long long m = maskT[tt][j];
                    int base = j * 64;
                    while (m) {
                        int idx = base + (int)__builtin_ctzll(m);
                        m &= m - 1;
                        float wv = WoutT[(size_t)idx * O_SIZE + o];
                        RES_ADD(idx, wv);
                    }
                }
                h2buf[tt][o] = __fadd_rn(__fadd_rn(e0, e1), __fadd_rn(e2, e3));
            }
        }
    }
    __syncthreads();

    // ---- phase 3: double-exp filter recurrence (20 threads) ----
    if (tid < O_SIZE) {
        float bo  = bout[tid];
        float flt = 0.f, outv = 0.f;
        out[((size_t)b * (T_STEPS + 1)) * O_SIZE + tid] = bo;   // t = 0 row
        for (int tt = 0; tt < T_STEPS; ++tt) {
            float h2   = h2buf[tt][tid];
            float nflt = __fadd_rn(__fmul_rn(ALPHA, flt), h2);
            float nout = __fadd_rn(__fmul_rn(BETA, outv), flt);  // OLD flt
            flt = nflt; outv = nout;
            out[((size_t)b * (T_STEPS + 1) + (tt + 1)) * O_SIZE + tid] = __fadd_rn(nout, bo);
        }
    }
}

// ---------------- reg loss ----------------
__global__ void reg_kernel(const int* __restrict__ g0,
                           const int* __restrict__ g1,
                           float* __restrict__ out_reg) {
    int tid = threadIdx.x;     // 512 threads
    double v0 = (double)g0[tid], v1 = (double)g1[tid];
    double tot = v0 + v1;
    double sq  = v0 * v0 + v1 * v1;
    for (int off = 32; off; off >>= 1) {
        tot += __shfl_down(tot, off, 64);
        sq  += __shfl_down(sq,  off, 64);
    }
    __shared__ double stot[8], ssq[8];
    if ((tid & 63) == 0) { stot[tid >> 6] = tot; ssq[tid >> 6] = sq; }
    __syncthreads();
    if (tid == 0) {
        double Tt = 0.0, Sq = 0.0;
        for (int w = 0; w < 8; ++w) { Tt += stot[w]; Sq += ssq[w]; }
        double reg = REG * (Tt / 26214400.0 + Sq / 512.0);
        *out_reg = (float)reg;
    }
}

extern "C" void kernel_launch(void* const* d_in, const int* in_sizes, int n_in,
                              void* d_out, int out_size, void* d_ws, size_t ws_size,
                              hipStream_t stream) {
    const float* spikes = (const float*)d_in[0];   // (512,100,700)
    const float* W0     = (const float*)d_in[1];   // (512,700)
    const float* W1     = (const float*)d_in[2];   // (512,512)
    const float* Wrec   = (const float*)d_in[3];   // (512,512)
    const float* Wout   = (const float*)d_in[4];   // (20,512)
    const float* bout   = (const float*)d_in[5];   // (20,)
    float* out = (float*)d_out;

    float* W0T   = (float*)d_ws;                       // 700*512 f32
    float* W1T   = W0T   + (size_t)I_SIZE * H_SIZE;    // 512*512
    float* WrecT = W1T   + (size_t)H_SIZE * H_SIZE;    // 512*512
    float* WoutT = WrecT + (size_t)H_SIZE * H_SIZE;    // 512*20
    int*   gcnt0 = (int*)(WoutT + (size_t)H_SIZE * O_SIZE);
    int*   gcnt1 = gcnt0 + H_SIZE;

    int n;
    n = H_SIZE * I_SIZE;
    transpose_kernel<<<(n + 255) / 256, 256, 0, stream>>>(W0, W0T, H_SIZE, I_SIZE);
    n = H_SIZE * H_SIZE;
    transpose_kernel<<<(n + 255) / 256, 256, 0, stream>>>(W1, W1T, H_SIZE, H_SIZE);
    transpose_kernel<<<(n + 255) / 256, 256, 0, stream>>>(Wrec, WrecT, H_SIZE, H_SIZE);
    n = O_SIZE * H_SIZE;
    transpose_kernel<<<(n + 255) / 256, 256, 0, stream>>>(Wout, WoutT, O_SIZE, H_SIZE);

    init_counts_kernel<<<1, 1024, 0, stream>>>(gcnt0);

    snn_sparse3_kernel<<<B_SIZE, H_SIZE, 0, stream>>>(spikes, W0T, W1T, WrecT, WoutT,
                                                      bout, out, gcnt0, gcnt1);

    reg_kernel<<<1, H_SIZE, 0, stream>>>(gcnt0, gcnt1,
                                         out + (size_t)B_SIZE * (T_STEPS + 1) * O_SIZE);
}